// Round 8
// baseline (24.647 us; speedup 1.0000x reference)
//
#include <hip/hip_runtime.h>
#include <math.h>

#ifndef M_PI
#define M_PI 3.14159265358979323846
#endif

#define IMGW 1024
#define SIDX(m,n) ((m)*9 - ((m)*((m)-1))/2 + ((n)-(m)))

typedef float f32x2 __attribute__((ext_vector_type(2)));

// ---- packed f32 (VOP3P) helpers: 2 FLOPs per issue slot --------------------
__device__ __forceinline__ f32x2 pk_fma(f32x2 a, f32x2 b, f32x2 c) {
    f32x2 d;
    asm("v_pk_fma_f32 %0, %1, %2, %3" : "=v"(d) : "v"(a), "v"(b), "v"(c));
    return d;
}
__device__ __forceinline__ f32x2 pk_mul(f32x2 a, f32x2 b) {
    f32x2 d;
    asm("v_pk_mul_f32 %0, %1, %2" : "=v"(d) : "v"(a), "v"(b));
    return d;
}
__device__ __forceinline__ f32x2 pk_add(f32x2 a, f32x2 b) {
    f32x2 d;
    asm("v_pk_add_f32 %0, %1, %2" : "=v"(d) : "v"(a), "v"(b));
    return d;
}

// upper-triangle index for 6x6 symmetric (21 entries), mirror-safe
__device__ __host__ constexpr int ut(int i, int j) {
    return (i <= j) ? (i * 6 - (i * (i - 1)) / 2 + (j - i))
                    : (j * 6 - (j * (j - 1)) / 2 + (i - j));
}

// Masked pure-xy moments for the 4 pad patterns (none/top/left/corner).
__device__ __constant__ float PURE[4][14] = {
    {3616.f, 3616.f, 1936.f, 256.f, 256.f, -512.f, -512.f, -176.f, -176.f, 352.f, 352.f, 16.f, -32.f, -32.f},
    {3164.f, 1568.f, 1232.f,   0.f,   0.f, -448.f,    0.f,    0.f, -112.f, 308.f, 224.f,  0.f, -28.f,   0.f},
    {1568.f, 3164.f, 1232.f,   0.f,   0.f,    0.f, -448.f, -112.f,    0.f, 224.f, 308.f,  0.f,   0.f, -28.f},
    {1372.f, 1372.f,  784.f,   0.f,   0.f,    0.f,    0.f,    0.f,    0.f, 196.f, 196.f,  0.f,   0.f,   0.f}
};
enum { P_U4, P_V4, P_U2V2, P_U3V, P_UV3, P_U3, P_V3, P_U2V, P_UV2, P_U2, P_V2, P_UV, P_U, P_V };

// ------------- symmetric-storage Jacobi, parallel-ordered rounds -----------
template<int P, int Q>
__device__ __forceinline__ void jangle(const float (&A)[21], float& c, float& s, float& t) {
    float apq = A[ut(P,Q)];
    float tau = (A[ut(Q,Q)] - A[ut(P,P)]) * __builtin_amdgcn_rcpf(2.0f * apq);
    float tt = copysignf(__builtin_amdgcn_rcpf(fabsf(tau) + sqrtf(fmaf(tau, tau, 1.0f))), tau);
    t = (fabsf(apq) > 1e-20f) ? tt : 0.0f;
    c = __builtin_amdgcn_rsqf(fmaf(t, t, 1.0f));
    s = t * c;
}

// A: scalar upper-tri update; VC: column-major packed eigvec accum (2 rows/f32x2)
template<int P, int Q>
__device__ __forceinline__ void japply(float (&A)[21], f32x2 (&VC)[6][3], float c, float s, float t) {
    #pragma unroll
    for (int k = 0; k < 6; ++k) {
        if (k != P && k != Q) {
            float akp = A[ut(k,P)], akq = A[ut(k,Q)];
            A[ut(k,P)] = fmaf(c, akp, -s * akq);
            A[ut(k,Q)] = fmaf(s, akp, c * akq);
        }
    }
    float apq = A[ut(P,Q)];
    A[ut(P,P)] = fmaf(-t, apq, A[ut(P,P)]);
    A[ut(Q,Q)] = fmaf( t, apq, A[ut(Q,Q)]);
    A[ut(P,Q)] = 0.0f;
    f32x2 cc = {c, c}, ss = {s, s}, ns = {-s, -s};
    #pragma unroll
    for (int h = 0; h < 3; ++h) {
        f32x2 vp = VC[P][h], vq = VC[Q][h];
        VC[P][h] = pk_fma(cc, vp, pk_mul(ns, vq));
        VC[Q][h] = pk_fma(cc, vq, pk_mul(ss, vp));
    }
}

template<int P0,int Q0,int P1,int Q1,int P2,int Q2>
__device__ __forceinline__ void jround3(float (&A)[21], f32x2 (&VC)[6][3]) {
    float c0,s0,t0,c1,s1,t1,c2,s2,t2;
    jangle<P0,Q0>(A, c0, s0, t0);   // disjoint pivots: 3 independent chains
    jangle<P1,Q1>(A, c1, s1, t1);
    jangle<P2,Q2>(A, c2, s2, t2);
    japply<P0,Q0>(A, VC, c0, s0, t0);
    japply<P1,Q1>(A, VC, c1, s1, t1);
    japply<P2,Q2>(A, VC, c2, s2, t2);
}

__device__ __forceinline__ void jacobi6f(float (&A)[21], f32x2 (&VC)[6][3], int sweeps) {
    #pragma unroll
    for (int j = 0; j < 6; ++j)
        #pragma unroll
        for (int h = 0; h < 3; ++h)
            VC[j][h] = f32x2{(2*h == j) ? 1.0f : 0.0f, (2*h+1 == j) ? 1.0f : 0.0f};
    for (int sw = 0; sw < sweeps; ++sw) {
        jround3<0,5, 1,4, 2,3>(A, VC);
        jround3<0,4, 3,5, 1,2>(A, VC);
        jround3<0,3, 2,4, 1,5>(A, VC);
        jround3<0,2, 1,3, 4,5>(A, VC);
        jround3<0,1, 2,5, 3,4>(A, VC);
    }
}

// ---------------- Schur complement S -> A6 (precision T) -------------------
template<typename T>
__device__ __forceinline__ void schur6(const T (&S)[45], float (&A6)[6][6]) {
    T g00 = S[SIDX(6,6)], g01 = S[SIDX(6,7)], g02 = S[SIDX(6,8)];
    T g11 = S[SIDX(7,7)], g12 = S[SIDX(7,8)], g22 = S[SIDX(8,8)];
    T c00 = g11 * g22 - g12 * g12;
    T c01 = g02 * g12 - g01 * g22;
    T c02 = g01 * g12 - g02 * g11;
    T det = g00 * c00 + g01 * c01 + g02 * c02;
    T invdet = (T)1 / det;
    T gi00 = c00 * invdet, gi01 = c01 * invdet, gi02 = c02 * invdet;
    T gi11 = (g00 * g22 - g02 * g02) * invdet;
    T gi12 = (g01 * g02 - g00 * g12) * invdet;
    T gi22 = (g00 * g11 - g01 * g01) * invdet;

    T B0[6], B1[6], B2[6], T0[6], T1[6], T2[6];
    #pragma unroll
    for (int m = 0; m < 6; ++m) {
        B0[m] = S[SIDX(m,6)]; B1[m] = S[SIDX(m,7)]; B2[m] = S[SIDX(m,8)];
    }
    #pragma unroll
    for (int m = 0; m < 6; ++m) {
        T0[m] = gi00 * B0[m] + gi01 * B1[m] + gi02 * B2[m];
        T1[m] = gi01 * B0[m] + gi11 * B1[m] + gi12 * B2[m];
        T2[m] = gi02 * B0[m] + gi12 * B1[m] + gi22 * B2[m];
    }
    #pragma unroll
    for (int m = 0; m < 6; ++m)
        #pragma unroll
        for (int n = m; n < 6; ++n) {
            T val = S[SIDX(m,n)] - (B0[m] * T0[n] + B1[m] * T1[n] + B2[m] * T2[n]);
            A6[m][n] = (float)val; A6[n][m] = (float)val;
        }
}

// 19 depth-weighted moments, packed over pixel pairs (f32x2 accumulators)
struct Wm {
    float W1_u,W1_v,W1_uu,W1_uv,W1_vv,W1_u3,W1_uuv,W1_uvv,W1_v3;
    float W2_1,W2_u,W2_v,W2_uu,W2_uv,W2_vv;
    float W3_1,W3_u,W3_v,W4_1;
};

__device__ __forceinline__ void accum_moments(const f32x2 (&wvp)[32], Wm& W) {
    const f32x2 CU[4]  = {{-4.f,-3.f},{-2.f,-1.f},{0.f,1.f},{2.f,3.f}};
    const f32x2 CU2[4] = {{16.f,9.f},{4.f,1.f},{0.f,1.f},{4.f,9.f}};
    const f32x2 CU3[4] = {{-64.f,-27.f},{-8.f,-1.f},{0.f,1.f},{8.f,27.f}};
    const f32x2 VB[8]  = {{-4.f,-4.f},{-3.f,-3.f},{-2.f,-2.f},{-1.f,-1.f},{0.f,0.f},{1.f,1.f},{2.f,2.f},{3.f,3.f}};
    const f32x2 V2B[8] = {{16.f,16.f},{9.f,9.f},{4.f,4.f},{1.f,1.f},{0.f,0.f},{1.f,1.f},{4.f,4.f},{9.f,9.f}};
    const f32x2 V3B[8] = {{-64.f,-64.f},{-27.f,-27.f},{-8.f,-8.f},{-1.f,-1.f},{0.f,0.f},{1.f,1.f},{8.f,8.f},{27.f,27.f}};

    f32x2 u={0,0}, v={0,0}, uu={0,0}, uv={0,0}, vv={0,0}, u3={0,0}, uuv={0,0}, uvv={0,0}, v3={0,0};
    f32x2 q1={0,0}, qu={0,0}, qv={0,0}, quu={0,0}, quv={0,0}, qvv={0,0};
    f32x2 c1={0,0}, cu={0,0}, cv={0,0}, h1={0,0};

    #pragma unroll
    for (int r = 0; r < 8; ++r) {
        #pragma unroll
        for (int cp = 0; cp < 4; ++cp) {
            f32x2 wp  = wvp[r*4+cp];
            f32x2 w2p = pk_mul(wp, wp);
            f32x2 w3p = pk_mul(w2p, wp);
            f32x2 uw  = pk_mul(CU[cp], wp);
            f32x2 u2w = pk_mul(CU2[cp], wp);
            f32x2 uw2 = pk_mul(CU[cp], w2p);
            u   = pk_add(u, uw);
            v   = pk_fma(VB[r], wp, v);
            uu  = pk_add(uu, u2w);
            uv  = pk_fma(VB[r], uw, uv);
            vv  = pk_fma(V2B[r], wp, vv);
            u3  = pk_fma(CU3[cp], wp, u3);
            uuv = pk_fma(VB[r], u2w, uuv);
            uvv = pk_fma(V2B[r], uw, uvv);
            v3  = pk_fma(V3B[r], wp, v3);
            q1  = pk_fma(wp, wp, q1);
            qu  = pk_add(qu, uw2);
            qv  = pk_fma(VB[r], w2p, qv);
            quu = pk_fma(CU2[cp], w2p, quu);
            quv = pk_fma(VB[r], uw2, quv);
            qvv = pk_fma(V2B[r], w2p, qvv);
            c1  = pk_add(c1, w3p);
            cu  = pk_fma(CU[cp], w3p, cu);
            cv  = pk_fma(VB[r], w3p, cv);
            h1  = pk_fma(w2p, w2p, h1);
        }
    }
    W.W1_u  = u.x + u.y;    W.W1_v  = v.x + v.y;    W.W1_uu = uu.x + uu.y;
    W.W1_uv = uv.x + uv.y;  W.W1_vv = vv.x + vv.y;  W.W1_u3 = u3.x + u3.y;
    W.W1_uuv= uuv.x + uuv.y;W.W1_uvv= uvv.x + uvv.y;W.W1_v3 = v3.x + v3.y;
    W.W2_1  = q1.x + q1.y;  W.W2_u  = qu.x + qu.y;  W.W2_v  = qv.x + qv.y;
    W.W2_uu = quu.x + quu.y;W.W2_uv = quv.x + quv.y;W.W2_vv = qvv.x + qvv.y;
    W.W3_1  = c1.x + c1.y;  W.W3_u  = cu.x + cu.y;  W.W3_v  = cv.x + cv.y;
    W.W4_1  = h1.x + h1.y;
}

// 512 threads/block = 8 waves/block = 2 waves per SIMD: co-resident waves
// fill each other's dependency-stall slots and share a warm I$.
__global__ __launch_bounds__(512, 2)
void curv_kernel(const float* __restrict__ depth, float* __restrict__ out) {
    unsigned k = blockIdx.x * 512u + threadIdx.x;
    if (k >= 16384u) return;

    // Partition: 252 exact waves interior (excl. (127,127)); 4 exact waves
    // boundary + (127,127). No wave mixes the two code paths.
    int pi, pj;
    bool boundary;
    if (k < 16128u) {
        pi = 1 + (int)(k / 127u);
        pj = 1 + (int)(k % 127u);
        boundary = false;
    } else {
        unsigned b = k - 16128u;        // 0..255
        if (b < 128u)      { pi = 0; pj = (int)b; }
        else if (b < 255u) { pi = (int)(b - 127u); pj = 0; }
        else               { pi = 127; pj = 127; }
        boundary = true;
    }

    float A6[6][6];

    if (!boundary) {
        // aligned float4 loads: 3 chunks/row covering cols 8pj-4 .. 8pj+8
        const float* rowbase = depth + (pi * 8 - 1) * IMGW + (pj * 8 - 4);
        float4 F[8][3];
        #pragma unroll
        for (int r = 0; r < 8; ++r) {
            const float4* rp = reinterpret_cast<const float4*>(rowbase + r * IMGW);
            F[r][0] = rp[0]; F[r][1] = rp[1]; F[r][2] = rp[2];
        }
        float d36 = F[4][1].w;           // row 4, col 8pj+3
        f32x2 wvp[32];
        #pragma unroll
        for (int r = 0; r < 8; ++r) {
            wvp[r*4+0] = f32x2{F[r][0].w - d36, F[r][1].x - d36};
            wvp[r*4+1] = f32x2{F[r][1].y - d36, F[r][1].z - d36};
            wvp[r*4+2] = f32x2{F[r][1].w - d36, F[r][2].x - d36};
            wvp[r*4+3] = f32x2{F[r][2].y - d36, F[r][2].z - d36};
        }

        Wm W;
        accum_moments(wvp, W);

        float S[45];
        S[SIDX(0,0)] = 3616.0f;   S[SIDX(0,1)] = 1936.0f;  S[SIDX(0,2)] = W.W2_uu;
        S[SIDX(0,3)] = 512.0f;    S[SIDX(0,4)] = 2.0f*W.W1_u3; S[SIDX(0,5)] = 2.0f*W.W1_uuv;
        S[SIDX(0,6)] = -1024.0f;  S[SIDX(0,7)] = -352.0f;  S[SIDX(0,8)] = 2.0f*W.W1_uu;
        S[SIDX(1,1)] = 3616.0f;   S[SIDX(1,2)] = W.W2_vv;  S[SIDX(1,3)] = 512.0f;
        S[SIDX(1,4)] = 2.0f*W.W1_uvv; S[SIDX(1,5)] = 2.0f*W.W1_v3;
        S[SIDX(1,6)] = -352.0f;   S[SIDX(1,7)] = -1024.0f; S[SIDX(1,8)] = 2.0f*W.W1_vv;
        S[SIDX(2,2)] = W.W4_1;    S[SIDX(2,3)] = 2.0f*W.W2_uv;
        S[SIDX(2,4)] = 2.0f*W.W3_u; S[SIDX(2,5)] = 2.0f*W.W3_v;
        S[SIDX(2,6)] = 2.0f*W.W2_u; S[SIDX(2,7)] = 2.0f*W.W2_v; S[SIDX(2,8)] = 2.0f*W.W3_1;
        S[SIDX(3,3)] = 7744.0f;   S[SIDX(3,4)] = 4.0f*W.W1_uuv; S[SIDX(3,5)] = 4.0f*W.W1_uvv;
        S[SIDX(3,6)] = -704.0f;   S[SIDX(3,7)] = -704.0f;  S[SIDX(3,8)] = 4.0f*W.W1_uv;
        S[SIDX(4,4)] = 4.0f*W.W2_uu; S[SIDX(4,5)] = 4.0f*W.W2_uv;
        S[SIDX(4,6)] = 4.0f*W.W1_uu; S[SIDX(4,7)] = 4.0f*W.W1_uv; S[SIDX(4,8)] = 4.0f*W.W2_u;
        S[SIDX(5,5)] = 4.0f*W.W2_vv;
        S[SIDX(5,6)] = 4.0f*W.W1_uv; S[SIDX(5,7)] = 4.0f*W.W1_vv; S[SIDX(5,8)] = 4.0f*W.W2_v;
        S[SIDX(6,6)] = 1408.0f;   S[SIDX(6,7)] = 64.0f;    S[SIDX(6,8)] = 4.0f*W.W1_u;
        S[SIDX(7,7)] = 1408.0f;   S[SIDX(7,8)] = 4.0f*W.W1_v;
        S[SIDX(8,8)] = 4.0f*W.W2_1;
        schur6<float>(S, A6);
    } else {
        bool top = (pi == 0), left = (pj == 0);
        int pat = (top ? 1 : 0) + (left ? 2 : 0);
        int baseR = pi * 8 - 1, baseC = pj * 8 - 1;
        float d36 = depth[(pi * 8 + 3) * IMGW + (pj * 8 + 3)];
        float wv[64];
        #pragma unroll
        for (int r = 0; r < 8; ++r) {
            int ir = max(baseR + r, 0);
            #pragma unroll
            for (int c = 0; c < 8; ++c) {
                int ic = max(baseC + c, 0);
                wv[r * 8 + c] = depth[ir * IMGW + ic];
            }
        }
        #pragma unroll
        for (int r = 0; r < 8; ++r)
            #pragma unroll
            for (int c = 0; c < 8; ++c) {
                bool pad = (top && r == 0) || (left && c == 0);
                wv[r * 8 + c] = pad ? 0.0f : (wv[r * 8 + c] - d36);
            }
        f32x2 wvp[32];
        #pragma unroll
        for (int i = 0; i < 32; ++i) wvp[i] = f32x2{wv[2*i], wv[2*i+1]};

        Wm W;
        accum_moments(wvp, W);

        const float* P = PURE[pat];
        float S32[45];
        S32[SIDX(0,0)] = P[P_U4];    S32[SIDX(0,1)] = P[P_U2V2]; S32[SIDX(0,2)] = W.W2_uu;
        S32[SIDX(0,3)] = 2.0f*P[P_U3V]; S32[SIDX(0,4)] = 2.0f*W.W1_u3; S32[SIDX(0,5)] = 2.0f*W.W1_uuv;
        S32[SIDX(0,6)] = 2.0f*P[P_U3]; S32[SIDX(0,7)] = 2.0f*P[P_U2V]; S32[SIDX(0,8)] = 2.0f*W.W1_uu;
        S32[SIDX(1,1)] = P[P_V4];    S32[SIDX(1,2)] = W.W2_vv;   S32[SIDX(1,3)] = 2.0f*P[P_UV3];
        S32[SIDX(1,4)] = 2.0f*W.W1_uvv; S32[SIDX(1,5)] = 2.0f*W.W1_v3;
        S32[SIDX(1,6)] = 2.0f*P[P_UV2]; S32[SIDX(1,7)] = 2.0f*P[P_V3]; S32[SIDX(1,8)] = 2.0f*W.W1_vv;
        S32[SIDX(2,2)] = W.W4_1;     S32[SIDX(2,3)] = 2.0f*W.W2_uv;
        S32[SIDX(2,4)] = 2.0f*W.W3_u; S32[SIDX(2,5)] = 2.0f*W.W3_v;
        S32[SIDX(2,6)] = 2.0f*W.W2_u; S32[SIDX(2,7)] = 2.0f*W.W2_v; S32[SIDX(2,8)] = 2.0f*W.W3_1;
        S32[SIDX(3,3)] = 4.0f*P[P_U2V2]; S32[SIDX(3,4)] = 4.0f*W.W1_uuv; S32[SIDX(3,5)] = 4.0f*W.W1_uvv;
        S32[SIDX(3,6)] = 4.0f*P[P_U2V]; S32[SIDX(3,7)] = 4.0f*P[P_UV2]; S32[SIDX(3,8)] = 4.0f*W.W1_uv;
        S32[SIDX(4,4)] = 4.0f*W.W2_uu; S32[SIDX(4,5)] = 4.0f*W.W2_uv;
        S32[SIDX(4,6)] = 4.0f*W.W1_uu; S32[SIDX(4,7)] = 4.0f*W.W1_uv; S32[SIDX(4,8)] = 4.0f*W.W2_u;
        S32[SIDX(5,5)] = 4.0f*W.W2_vv;
        S32[SIDX(5,6)] = 4.0f*W.W1_uv; S32[SIDX(5,7)] = 4.0f*W.W1_vv; S32[SIDX(5,8)] = 4.0f*W.W2_v;
        S32[SIDX(6,6)] = 4.0f*P[P_U2]; S32[SIDX(6,7)] = 4.0f*P[P_UV]; S32[SIDX(6,8)] = 4.0f*W.W1_u;
        S32[SIDX(7,7)] = 4.0f*P[P_V2]; S32[SIDX(7,8)] = 4.0f*W.W1_v;
        S32[SIDX(8,8)] = 4.0f*W.W2_1;

        // exact f64 rank-1 far-point update for the coincident pad pixels
        double m = (double)((top ? 8 : 0) + (left ? 8 : 0) - ((top && left) ? 1 : 0));
        double xf = -(double)(pj * 8 + 3);
        double yf = -(double)(pi * 8 + 3);
        double df = -(double)d36;
        double d9f[9];
        d9f[0] = xf * xf; d9f[1] = yf * yf; d9f[2] = df * df;
        d9f[3] = 2.0 * xf * yf; d9f[4] = 2.0 * xf * df; d9f[5] = 2.0 * yf * df;
        d9f[6] = 2.0 * xf; d9f[7] = 2.0 * yf; d9f[8] = 2.0 * df;
        double S64[45];
        #pragma unroll
        for (int mm = 0; mm < 9; ++mm)
            #pragma unroll
            for (int nn = mm; nn < 9; ++nn)
                S64[SIDX(mm,nn)] = (double)S32[SIDX(mm,nn)] + m * d9f[mm] * d9f[nn];
        schur6<double>(S64, A6);
    }

    // ---- Cholesky A + ridge = L L^T ----
    float tr = A6[0][0] + A6[1][1] + A6[2][2] + A6[3][3] + A6[4][4] + A6[5][5];
    float ridge = 1e-6f * tr + 1e-30f;
    float dfloor = 1e-12f * tr + 1e-30f;
    float L[6][6];
    #pragma unroll
    for (int i = 0; i < 6; ++i)
        #pragma unroll
        for (int j = 0; j < 6; ++j)
            L[i][j] = 0.0f;
    #pragma unroll
    for (int j = 0; j < 6; ++j) {
        float d = A6[j][j] + ridge;
        #pragma unroll
        for (int kk = 0; kk < 6; ++kk)
            if (kk < j) d = fmaf(-L[j][kk], L[j][kk], d);
        d = fmaxf(d, dfloor);
        float sd = sqrtf(d);
        float isd = __builtin_amdgcn_rcpf(sd);
        L[j][j] = sd;
        #pragma unroll
        for (int i = 0; i < 6; ++i) {
            if (i > j) {
                float v = A6[i][j];
                #pragma unroll
                for (int kk = 0; kk < 6; ++kk)
                    if (kk < j) v = fmaf(-L[i][kk], L[j][kk], v);
                L[i][j] = v * isd;
            }
        }
    }

    // ---- Ms = L^T Cinv L (upper-tri storage); Cinv = blockdiag((J-I)/2, -I/4)
    float N[6][6];
    #pragma unroll
    for (int j = 0; j < 6; ++j) {
        N[0][j] = 0.5f * (L[1][j] + L[2][j]);
        N[1][j] = 0.5f * (L[0][j] + L[2][j]);
        N[2][j] = 0.5f * (L[0][j] + L[1][j]);
        N[3][j] = -0.25f * L[3][j];
        N[4][j] = -0.25f * L[4][j];
        N[5][j] = -0.25f * L[5][j];
    }
    float Ms[21];
    #pragma unroll
    for (int i = 0; i < 6; ++i)
        #pragma unroll
        for (int j = 0; j < 6; ++j) {
            if (i <= j) {
                float acc = 0.0f;
                #pragma unroll
                for (int kk = 0; kk < 6; ++kk)
                    acc = fmaf(L[kk][i], N[kk][j], acc);
                Ms[ut(i,j)] = acc;
            }
        }

    // ---- Jacobi (symmetric storage + packed V, 3 sweeps) ----
    f32x2 VC[6][3];
    jacobi6f(Ms, VC, 3);
    float l2max = Ms[ut(0,0)];
    int imax = 0;
    #pragma unroll
    for (int i = 1; i < 6; ++i) {
        float di = Ms[ut(i,i)];
        if (di > l2max) { l2max = di; imax = i; }
    }
    float y6[6];
    #pragma unroll
    for (int i = 0; i < 6; ++i) {
        float acc = 0.0f;
        #pragma unroll
        for (int jj = 0; jj < 6; ++jj) {
            float vij = (i & 1) ? VC[jj][i >> 1].y : VC[jj][i >> 1].x;
            acc += (jj == imax) ? vij : 0.0f;
        }
        y6[i] = acc;
    }

    // ---- v = L^{-T} y (back-substitution) ----
    float v5 = y6[5] * __builtin_amdgcn_rcpf(L[5][5]);
    float v4 = (y6[4] - L[5][4]*v5) * __builtin_amdgcn_rcpf(L[4][4]);
    float v3 = (y6[3] - L[4][3]*v4 - L[5][3]*v5) * __builtin_amdgcn_rcpf(L[3][3]);
    float v2 = (y6[2] - L[3][2]*v3 - L[4][2]*v4 - L[5][2]*v5) * __builtin_amdgcn_rcpf(L[2][2]);
    float v1 = (y6[1] - L[2][1]*v2 - L[3][1]*v3 - L[4][1]*v4 - L[5][1]*v5) * __builtin_amdgcn_rcpf(L[1][1]);
    float v0 = (y6[0] - L[1][0]*v1 - L[2][0]*v2 - L[3][0]*v3 - L[4][0]*v4 - L[5][0]*v5) * __builtin_amdgcn_rcpf(L[0][0]);

    // ---- 3x3 symmetric eigenvalue ratio (closed form, f32) ----
    float a = v0, b = v1, cc = v2, d = v3, e = v4, f = v5;
    float ev0, ev1, ev2;
    float off = d * d + e * e + f * f;
    if (off == 0.0f) {
        ev0 = a; ev1 = b; ev2 = cc;
    } else {
        float q = (a + b + cc) * (1.0f / 3.0f);
        float p2 = (a-q)*(a-q) + (b-q)*(b-q) + (cc-q)*(cc-q) + 2.0f * off;
        float p = sqrtf(p2 * (1.0f / 6.0f));
        float ip = __builtin_amdgcn_rcpf(p);
        float b00 = (a - q) * ip, b11 = (b - q) * ip, b22 = (cc - q) * ip;
        float b01 = d * ip, b02 = e * ip, b12 = f * ip;
        float detB = b00 * (b11 * b22 - b12 * b12)
                   - b01 * (b01 * b22 - b12 * b02)
                   + b02 * (b01 * b12 - b11 * b02);
        float rr = 0.5f * detB;
        rr = fminf(1.0f, fmaxf(-1.0f, rr));
        float phi = acosf(rr) * (1.0f / 3.0f);
        ev0 = q + 2.0f * p * cosf(phi);
        ev2 = q + 2.0f * p * cosf(phi + (float)(2.0 * M_PI / 3.0));
        ev1 = 3.0f * q - ev0 - ev2;
    }
    float A0 = fabsf(ev0), A1 = fabsf(ev1), A2 = fabsf(ev2);
    float mx = fmaxf(A0, fmaxf(A1, A2));
    float mn = fminf(A0, fminf(A1, A2));
    float simi = sqrtf(fmaxf(mn, 1e-9f) / fmaxf(mx, 1e-9f));

    out[pi * 128 + pj] = simi;
}

extern "C" void kernel_launch(void* const* d_in, const int* in_sizes, int n_in,
                              void* d_out, int out_size, void* d_ws, size_t ws_size,
                              hipStream_t stream) {
    const float* depth = (const float*)d_in[0];
    float* out = (float*)d_out;
    curv_kernel<<<dim3(32), dim3(512), 0, stream>>>(depth, out);
}

// Round 11
// 16.491 us; speedup vs baseline: 1.4946x; 1.4946x over previous
//
#include <hip/hip_runtime.h>
#include <math.h>

#ifndef M_PI
#define M_PI 3.14159265358979323846
#endif

#define IMGW 1024
#define SIDX(m,n) ((m)*9 - ((m)*((m)-1))/2 + ((n)-(m)))

typedef float f32x2 __attribute__((ext_vector_type(2)));

// ---- packed f32 (VOP3P) helpers: 2 FLOPs per issue slot --------------------
__device__ __forceinline__ f32x2 pk_fma(f32x2 a, f32x2 b, f32x2 c) {
    f32x2 d;
    asm("v_pk_fma_f32 %0, %1, %2, %3" : "=v"(d) : "v"(a), "v"(b), "v"(c));
    return d;
}
__device__ __forceinline__ f32x2 pk_mul(f32x2 a, f32x2 b) {
    f32x2 d;
    asm("v_pk_mul_f32 %0, %1, %2" : "=v"(d) : "v"(a), "v"(b));
    return d;
}
__device__ __forceinline__ f32x2 pk_add(f32x2 a, f32x2 b) {
    f32x2 d;
    asm("v_pk_add_f32 %0, %1, %2" : "=v"(d) : "v"(a), "v"(b));
    return d;
}

// upper-triangle index for 6x6 symmetric (21 entries), mirror-safe
__device__ __host__ constexpr int ut(int i, int j) {
    return (i <= j) ? (i * 6 - (i * (i - 1)) / 2 + (j - i))
                    : (j * 6 - (j * (j - 1)) / 2 + (i - j));
}

// Masked pure-xy moments for the 4 pad patterns (none/top/left/corner).
__device__ __constant__ float PURE[4][14] = {
    {3616.f, 3616.f, 1936.f, 256.f, 256.f, -512.f, -512.f, -176.f, -176.f, 352.f, 352.f, 16.f, -32.f, -32.f},
    {3164.f, 1568.f, 1232.f,   0.f,   0.f, -448.f,    0.f,    0.f, -112.f, 308.f, 224.f,  0.f, -28.f,   0.f},
    {1568.f, 3164.f, 1232.f,   0.f,   0.f,    0.f, -448.f, -112.f,    0.f, 224.f, 308.f,  0.f,   0.f, -28.f},
    {1372.f, 1372.f,  784.f,   0.f,   0.f,    0.f,    0.f,    0.f,    0.f, 196.f, 196.f,  0.f,   0.f,   0.f}
};
enum { P_U4, P_V4, P_U2V2, P_U3V, P_UV3, P_U3, P_V3, P_U2V, P_UV2, P_U2, P_V2, P_UV, P_U, P_V };

// ------------- symmetric-storage Jacobi, parallel-ordered rounds -----------
template<int P, int Q>
__device__ __forceinline__ void jangle(const float (&A)[21], float& c, float& s, float& t) {
    float apq = A[ut(P,Q)];
    float tau = (A[ut(Q,Q)] - A[ut(P,P)]) * __builtin_amdgcn_rcpf(2.0f * apq);
    float tt = copysignf(__builtin_amdgcn_rcpf(fabsf(tau) + sqrtf(fmaf(tau, tau, 1.0f))), tau);
    t = (fabsf(apq) > 1e-20f) ? tt : 0.0f;
    c = __builtin_amdgcn_rsqf(fmaf(t, t, 1.0f));
    s = t * c;
}

// A: scalar upper-tri update; VC: packed eigvec accum.
// Layout: VC[col][h] = {V[2h][col], V[2h+1][col]}  (first index = eigvec COLUMN)
template<int P, int Q>
__device__ __forceinline__ void japply(float (&A)[21], f32x2 (&VC)[6][3], float c, float s, float t) {
    #pragma unroll
    for (int k = 0; k < 6; ++k) {
        if (k != P && k != Q) {
            float akp = A[ut(k,P)], akq = A[ut(k,Q)];
            A[ut(k,P)] = fmaf(c, akp, -s * akq);
            A[ut(k,Q)] = fmaf(s, akp, c * akq);
        }
    }
    float apq = A[ut(P,Q)];
    A[ut(P,P)] = fmaf(-t, apq, A[ut(P,P)]);
    A[ut(Q,Q)] = fmaf( t, apq, A[ut(Q,Q)]);
    A[ut(P,Q)] = 0.0f;
    f32x2 cc = {c, c}, ss = {s, s}, ns = {-s, -s};
    #pragma unroll
    for (int h = 0; h < 3; ++h) {
        f32x2 vp = VC[P][h], vq = VC[Q][h];
        VC[P][h] = pk_fma(cc, vp, pk_mul(ns, vq));
        VC[Q][h] = pk_fma(cc, vq, pk_mul(ss, vp));
    }
}

template<int P0,int Q0,int P1,int Q1,int P2,int Q2>
__device__ __forceinline__ void jround3(float (&A)[21], f32x2 (&VC)[6][3]) {
    float c0,s0,t0,c1,s1,t1,c2,s2,t2;
    jangle<P0,Q0>(A, c0, s0, t0);   // disjoint pivots: 3 independent chains
    jangle<P1,Q1>(A, c1, s1, t1);
    jangle<P2,Q2>(A, c2, s2, t2);
    japply<P0,Q0>(A, VC, c0, s0, t0);
    japply<P1,Q1>(A, VC, c1, s1, t1);
    japply<P2,Q2>(A, VC, c2, s2, t2);
}

__device__ __forceinline__ void jacobi6f(float (&A)[21], f32x2 (&VC)[6][3], int sweeps) {
    #pragma unroll
    for (int j = 0; j < 6; ++j)
        #pragma unroll
        for (int h = 0; h < 3; ++h)
            VC[j][h] = f32x2{(2*h == j) ? 1.0f : 0.0f, (2*h+1 == j) ? 1.0f : 0.0f};
    for (int sw = 0; sw < sweeps; ++sw) {
        jround3<0,5, 1,4, 2,3>(A, VC);
        jround3<0,4, 3,5, 1,2>(A, VC);
        jround3<0,3, 2,4, 1,5>(A, VC);
        jround3<0,2, 1,3, 4,5>(A, VC);
        jround3<0,1, 2,5, 3,4>(A, VC);
    }
}

// ---------------- f32 Schur complement S -> A6 (shared by both paths) ------
__device__ __forceinline__ void schur6f(const float (&S)[45], float (&A6)[6][6]) {
    float g00 = S[SIDX(6,6)], g01 = S[SIDX(6,7)], g02 = S[SIDX(6,8)];
    float g11 = S[SIDX(7,7)], g12 = S[SIDX(7,8)], g22 = S[SIDX(8,8)];
    float c00 = g11 * g22 - g12 * g12;
    float c01 = g02 * g12 - g01 * g22;
    float c02 = g01 * g12 - g02 * g11;
    float det = g00 * c00 + g01 * c01 + g02 * c02;
    float invdet = 1.0f / det;
    float gi00 = c00 * invdet, gi01 = c01 * invdet, gi02 = c02 * invdet;
    float gi11 = (g00 * g22 - g02 * g02) * invdet;
    float gi12 = (g01 * g02 - g00 * g12) * invdet;
    float gi22 = (g00 * g11 - g01 * g01) * invdet;

    float B0[6], B1[6], B2[6], T0[6], T1[6], T2[6];
    #pragma unroll
    for (int m = 0; m < 6; ++m) {
        B0[m] = S[SIDX(m,6)]; B1[m] = S[SIDX(m,7)]; B2[m] = S[SIDX(m,8)];
    }
    #pragma unroll
    for (int m = 0; m < 6; ++m) {
        T0[m] = gi00 * B0[m] + gi01 * B1[m] + gi02 * B2[m];
        T1[m] = gi01 * B0[m] + gi11 * B1[m] + gi12 * B2[m];
        T2[m] = gi02 * B0[m] + gi12 * B1[m] + gi22 * B2[m];
    }
    #pragma unroll
    for (int m = 0; m < 6; ++m)
        #pragma unroll
        for (int n = m; n < 6; ++n) {
            float val = S[SIDX(m,n)] - (B0[m] * T0[n] + B1[m] * T1[n] + B2[m] * T2[n]);
            A6[m][n] = val; A6[n][m] = val;
        }
}

// 19 depth-weighted moments, packed over pixel pairs (f32x2 accumulators)
struct Wm {
    float W1_u,W1_v,W1_uu,W1_uv,W1_vv,W1_u3,W1_uuv,W1_uvv,W1_v3;
    float W2_1,W2_u,W2_v,W2_uu,W2_uv,W2_vv;
    float W3_1,W3_u,W3_v,W4_1;
};

__device__ __forceinline__ void accum_moments(const f32x2 (&wvp)[32], Wm& W) {
    const f32x2 CU[4]  = {{-4.f,-3.f},{-2.f,-1.f},{0.f,1.f},{2.f,3.f}};
    const f32x2 CU2[4] = {{16.f,9.f},{4.f,1.f},{0.f,1.f},{4.f,9.f}};
    const f32x2 CU3[4] = {{-64.f,-27.f},{-8.f,-1.f},{0.f,1.f},{8.f,27.f}};
    const f32x2 VB[8]  = {{-4.f,-4.f},{-3.f,-3.f},{-2.f,-2.f},{-1.f,-1.f},{0.f,0.f},{1.f,1.f},{2.f,2.f},{3.f,3.f}};
    const f32x2 V2B[8] = {{16.f,16.f},{9.f,9.f},{4.f,4.f},{1.f,1.f},{0.f,0.f},{1.f,1.f},{4.f,4.f},{9.f,9.f}};
    const f32x2 V3B[8] = {{-64.f,-64.f},{-27.f,-27.f},{-8.f,-8.f},{-1.f,-1.f},{0.f,0.f},{1.f,1.f},{8.f,8.f},{27.f,27.f}};

    f32x2 u={0,0}, v={0,0}, uu={0,0}, uv={0,0}, vv={0,0}, u3={0,0}, uuv={0,0}, uvv={0,0}, v3={0,0};
    f32x2 q1={0,0}, qu={0,0}, qv={0,0}, quu={0,0}, quv={0,0}, qvv={0,0};
    f32x2 c1={0,0}, cu={0,0}, cv={0,0}, h1={0,0};

    #pragma unroll
    for (int r = 0; r < 8; ++r) {
        #pragma unroll
        for (int cp = 0; cp < 4; ++cp) {
            f32x2 wp  = wvp[r*4+cp];
            f32x2 w2p = pk_mul(wp, wp);
            f32x2 w3p = pk_mul(w2p, wp);
            f32x2 uw  = pk_mul(CU[cp], wp);
            f32x2 u2w = pk_mul(CU2[cp], wp);
            f32x2 uw2 = pk_mul(CU[cp], w2p);
            u   = pk_add(u, uw);
            v   = pk_fma(VB[r], wp, v);
            uu  = pk_add(uu, u2w);
            uv  = pk_fma(VB[r], uw, uv);
            vv  = pk_fma(V2B[r], wp, vv);
            u3  = pk_fma(CU3[cp], wp, u3);
            uuv = pk_fma(VB[r], u2w, uuv);
            uvv = pk_fma(V2B[r], uw, uvv);
            v3  = pk_fma(V3B[r], wp, v3);
            q1  = pk_fma(wp, wp, q1);
            qu  = pk_add(qu, uw2);
            qv  = pk_fma(VB[r], w2p, qv);
            quu = pk_fma(CU2[cp], w2p, quu);
            quv = pk_fma(VB[r], uw2, quv);
            qvv = pk_fma(V2B[r], w2p, qvv);
            c1  = pk_add(c1, w3p);
            cu  = pk_fma(CU[cp], w3p, cu);
            cv  = pk_fma(VB[r], w3p, cv);
            h1  = pk_fma(w2p, w2p, h1);
        }
    }
    W.W1_u  = u.x + u.y;    W.W1_v  = v.x + v.y;    W.W1_uu = uu.x + uu.y;
    W.W1_uv = uv.x + uv.y;  W.W1_vv = vv.x + vv.y;  W.W1_u3 = u3.x + u3.y;
    W.W1_uuv= uuv.x + uuv.y;W.W1_uvv= uvv.x + uvv.y;W.W1_v3 = v3.x + v3.y;
    W.W2_1  = q1.x + q1.y;  W.W2_u  = qu.x + qu.y;  W.W2_v  = qv.x + qv.y;
    W.W2_uu = quu.x + quu.y;W.W2_uv = quv.x + quv.y;W.W2_vv = qvv.x + qvv.y;
    W.W3_1  = c1.x + c1.y;  W.W3_u  = cu.x + cu.y;  W.W3_v  = cv.x + cv.y;
    W.W4_1  = h1.x + h1.y;
}

// Assemble the 9x9 Gram from moments + pure-xy table (pat=0 interior consts)
__device__ __forceinline__ void buildS(const Wm& W, const float* P, float (&S)[45]) {
    S[SIDX(0,0)] = P[P_U4];    S[SIDX(0,1)] = P[P_U2V2]; S[SIDX(0,2)] = W.W2_uu;
    S[SIDX(0,3)] = 2.0f*P[P_U3V]; S[SIDX(0,4)] = 2.0f*W.W1_u3; S[SIDX(0,5)] = 2.0f*W.W1_uuv;
    S[SIDX(0,6)] = 2.0f*P[P_U3]; S[SIDX(0,7)] = 2.0f*P[P_U2V]; S[SIDX(0,8)] = 2.0f*W.W1_uu;
    S[SIDX(1,1)] = P[P_V4];    S[SIDX(1,2)] = W.W2_vv;   S[SIDX(1,3)] = 2.0f*P[P_UV3];
    S[SIDX(1,4)] = 2.0f*W.W1_uvv; S[SIDX(1,5)] = 2.0f*W.W1_v3;
    S[SIDX(1,6)] = 2.0f*P[P_UV2]; S[SIDX(1,7)] = 2.0f*P[P_V3]; S[SIDX(1,8)] = 2.0f*W.W1_vv;
    S[SIDX(2,2)] = W.W4_1;     S[SIDX(2,3)] = 2.0f*W.W2_uv;
    S[SIDX(2,4)] = 2.0f*W.W3_u; S[SIDX(2,5)] = 2.0f*W.W3_v;
    S[SIDX(2,6)] = 2.0f*W.W2_u; S[SIDX(2,7)] = 2.0f*W.W2_v; S[SIDX(2,8)] = 2.0f*W.W3_1;
    S[SIDX(3,3)] = 4.0f*P[P_U2V2]; S[SIDX(3,4)] = 4.0f*W.W1_uuv; S[SIDX(3,5)] = 4.0f*W.W1_uvv;
    S[SIDX(3,6)] = 4.0f*P[P_U2V]; S[SIDX(3,7)] = 4.0f*P[P_UV2]; S[SIDX(3,8)] = 4.0f*W.W1_uv;
    S[SIDX(4,4)] = 4.0f*W.W2_uu; S[SIDX(4,5)] = 4.0f*W.W2_uv;
    S[SIDX(4,6)] = 4.0f*W.W1_uu; S[SIDX(4,7)] = 4.0f*W.W1_uv; S[SIDX(4,8)] = 4.0f*W.W2_u;
    S[SIDX(5,5)] = 4.0f*W.W2_vv;
    S[SIDX(5,6)] = 4.0f*W.W1_uv; S[SIDX(5,7)] = 4.0f*W.W1_vv; S[SIDX(5,8)] = 4.0f*W.W2_v;
    S[SIDX(6,6)] = 4.0f*P[P_U2]; S[SIDX(6,7)] = 4.0f*P[P_UV]; S[SIDX(6,8)] = 4.0f*W.W1_u;
    S[SIDX(7,7)] = 4.0f*P[P_V2]; S[SIDX(7,8)] = 4.0f*W.W1_v;
    S[SIDX(8,8)] = 4.0f*W.W2_1;
}

__global__ __launch_bounds__(64, 1)
void curv_kernel(const float* __restrict__ depth, float* __restrict__ out) {
    unsigned k = blockIdx.x * 64u + threadIdx.x;
    if (k >= 16384u) return;

    // Partition: 252 exact waves interior (excl. (127,127)); 4 exact waves
    // boundary + (127,127). No wave mixes the two code paths.
    int pi, pj;
    bool boundary;
    if (k < 16128u) {
        pi = 1 + (int)(k / 127u);
        pj = 1 + (int)(k % 127u);
        boundary = false;
    } else {
        unsigned b = k - 16128u;        // 0..255
        if (b < 128u)      { pi = 0; pj = (int)b; }
        else if (b < 255u) { pi = (int)(b - 127u); pj = 0; }
        else               { pi = 127; pj = 127; }
        boundary = true;
    }

    float A6[6][6];

    if (!boundary) {
        // aligned float4 loads: 3 chunks/row covering cols 8pj-4 .. 8pj+8
        const float* rowbase = depth + (pi * 8 - 1) * IMGW + (pj * 8 - 4);
        float4 F[8][3];
        #pragma unroll
        for (int r = 0; r < 8; ++r) {
            const float4* rp = reinterpret_cast<const float4*>(rowbase + r * IMGW);
            F[r][0] = rp[0]; F[r][1] = rp[1]; F[r][2] = rp[2];
        }
        float d36 = F[4][1].w;           // row 4, col 8pj+3
        f32x2 wvp[32];
        #pragma unroll
        for (int r = 0; r < 8; ++r) {
            wvp[r*4+0] = f32x2{F[r][0].w - d36, F[r][1].x - d36};
            wvp[r*4+1] = f32x2{F[r][1].y - d36, F[r][1].z - d36};
            wvp[r*4+2] = f32x2{F[r][1].w - d36, F[r][2].x - d36};
            wvp[r*4+3] = f32x2{F[r][2].y - d36, F[r][2].z - d36};
        }
        Wm W;
        accum_moments(wvp, W);
        float S[45];
        buildS(W, PURE[0], S);
        schur6f(S, A6);
    } else {
        bool top = (pi == 0), left = (pj == 0);
        int pat = (top ? 1 : 0) + (left ? 2 : 0);
        int baseR = pi * 8 - 1, baseC = pj * 8 - 1;
        float d36 = depth[(pi * 8 + 3) * IMGW + (pj * 8 + 3)];
        float wv[64];
        #pragma unroll
        for (int r = 0; r < 8; ++r) {
            int ir = max(baseR + r, 0);
            #pragma unroll
            for (int c = 0; c < 8; ++c) {
                int ic = max(baseC + c, 0);
                wv[r * 8 + c] = depth[ir * IMGW + ic];
            }
        }
        #pragma unroll
        for (int r = 0; r < 8; ++r)
            #pragma unroll
            for (int c = 0; c < 8; ++c) {
                bool pad = (top && r == 0) || (left && c == 0);
                wv[r * 8 + c] = pad ? 0.0f : (wv[r * 8 + c] - d36);
            }
        f32x2 wvp[32];
        #pragma unroll
        for (int i = 0; i < 32; ++i) wvp[i] = f32x2{wv[2*i], wv[2*i+1]};

        Wm W;
        accum_moments(wvp, W);
        float S[45];                     // cloud-only (non-pad) Gram, f32
        buildS(W, PURE[pat], S);
        schur6f(S, A6);                  // A of the cloud

        // ---- exact rank-1 Schur update for the m coincident pad pixels ----
        // Schur(M + m d d^T) = Schur(M) + beta r r^T,
        //   r = d1 - S12 S22^{-1} d2,  beta = m / (1 + m d2^T S22^{-1} d2)
        double mass = (double)((top ? 8 : 0) + (left ? 8 : 0) - ((top && left) ? 1 : 0));
        double xf = -(double)(pj * 8 + 3);
        double yf = -(double)(pi * 8 + 3);
        double df = -(double)d36;
        double d1[6];
        d1[0] = xf * xf; d1[1] = yf * yf; d1[2] = df * df;
        d1[3] = 2.0 * xf * yf; d1[4] = 2.0 * xf * df; d1[5] = 2.0 * yf * df;
        double d2x = 2.0 * xf, d2y = 2.0 * yf, d2z = 2.0 * df;

        double g00 = S[SIDX(6,6)], g01 = S[SIDX(6,7)], g02 = S[SIDX(6,8)];
        double g11 = S[SIDX(7,7)], g12 = S[SIDX(7,8)], g22 = S[SIDX(8,8)];
        double c00 = g11 * g22 - g12 * g12;
        double c01 = g02 * g12 - g01 * g22;
        double c02 = g01 * g12 - g02 * g11;
        double det = g00 * c00 + g01 * c01 + g02 * c02;
        double inv = 1.0 / det;
        double gi00 = c00 * inv, gi01 = c01 * inv, gi02 = c02 * inv;
        double gi11 = (g00 * g22 - g02 * g02) * inv;
        double gi12 = (g01 * g02 - g00 * g12) * inv;
        double gi22 = (g00 * g11 - g01 * g01) * inv;
        double ux = gi00 * d2x + gi01 * d2y + gi02 * d2z;
        double uy = gi01 * d2x + gi11 * d2y + gi12 * d2z;
        double uz = gi02 * d2x + gi12 * d2y + gi22 * d2z;
        double alpha = d2x * ux + d2y * uy + d2z * uz;
        double beta = mass / (1.0 + mass * alpha);
        double rr[6];
        #pragma unroll
        for (int m = 0; m < 6; ++m)
            rr[m] = d1[m] - ((double)S[SIDX(m,6)] * ux +
                             (double)S[SIDX(m,7)] * uy +
                             (double)S[SIDX(m,8)] * uz);
        #pragma unroll
        for (int i = 0; i < 6; ++i)
            #pragma unroll
            for (int j = i; j < 6; ++j) {
                float upd = (float)((double)A6[i][j] + beta * rr[i] * rr[j]);
                A6[i][j] = upd; A6[j][i] = upd;
            }
    }

    // ---- Cholesky A + ridge = L L^T (isd saved for back-substitution) ----
    float tr = A6[0][0] + A6[1][1] + A6[2][2] + A6[3][3] + A6[4][4] + A6[5][5];
    float ridge = 1e-6f * tr + 1e-30f;
    float dfloor = 1e-12f * tr + 1e-30f;
    float L[6][6];
    float isd[6];
    #pragma unroll
    for (int i = 0; i < 6; ++i)
        #pragma unroll
        for (int j = 0; j < 6; ++j)
            L[i][j] = 0.0f;
    #pragma unroll
    for (int j = 0; j < 6; ++j) {
        float d = A6[j][j] + ridge;
        #pragma unroll
        for (int kk = 0; kk < 6; ++kk)
            if (kk < j) d = fmaf(-L[j][kk], L[j][kk], d);
        d = fmaxf(d, dfloor);
        float is = __builtin_amdgcn_rsqf(d);   // 1/sqrt(d)
        float sd = d * is;                     // sqrt(d)
        isd[j] = is;
        L[j][j] = sd;
        #pragma unroll
        for (int i = 0; i < 6; ++i) {
            if (i > j) {
                float v = A6[i][j];
                #pragma unroll
                for (int kk = 0; kk < 6; ++kk)
                    if (kk < j) v = fmaf(-L[i][kk], L[j][kk], v);
                L[i][j] = v * is;
            }
        }
    }

    // ---- Ms = L^T Cinv L (upper-tri storage); Cinv = blockdiag((J-I)/2, -I/4)
    float N[6][6];
    #pragma unroll
    for (int j = 0; j < 6; ++j) {
        N[0][j] = 0.5f * (L[1][j] + L[2][j]);
        N[1][j] = 0.5f * (L[0][j] + L[2][j]);
        N[2][j] = 0.5f * (L[0][j] + L[1][j]);
        N[3][j] = -0.25f * L[3][j];
        N[4][j] = -0.25f * L[4][j];
        N[5][j] = -0.25f * L[5][j];
    }
    float Ms[21];
    #pragma unroll
    for (int i = 0; i < 6; ++i)
        #pragma unroll
        for (int j = 0; j < 6; ++j) {
            if (i <= j) {
                float acc = 0.0f;
                #pragma unroll
                for (int kk = 0; kk < 6; ++kk)
                    acc = fmaf(L[kk][i], N[kk][j], acc);
                Ms[ut(i,j)] = acc;
            }
        }

    // ---- Jacobi (symmetric storage + packed V, 3 sweeps) ----
    f32x2 VC[6][3];
    jacobi6f(Ms, VC, 3);
    float l2max = Ms[ut(0,0)];
    int imax = 0;
    #pragma unroll
    for (int i = 1; i < 6; ++i) {
        float di = Ms[ut(i,i)];
        if (di > l2max) { l2max = di; imax = i; }
    }
    // Column imax of V: y6[i] = V[i][imax] = VC[imax][i>>1].(i&1 ? y : x).
    // imax is runtime -> masked sum over the first (column) index.
    float y6[6];
    #pragma unroll
    for (int i = 0; i < 6; ++i) {
        float acc = 0.0f;
        #pragma unroll
        for (int jj = 0; jj < 6; ++jj) {
            float vij = (i & 1) ? VC[jj][i >> 1].y : VC[jj][i >> 1].x;  // = V[i][jj]
            acc += (jj == imax) ? vij : 0.0f;
        }
        y6[i] = acc;
    }

    // ---- v = L^{-T} y (back-substitution, reusing isd) ----
    float v5 = y6[5] * isd[5];
    float v4 = (y6[4] - L[5][4]*v5) * isd[4];
    float v3 = (y6[3] - L[4][3]*v4 - L[5][3]*v5) * isd[3];
    float v2 = (y6[2] - L[3][2]*v3 - L[4][2]*v4 - L[5][2]*v5) * isd[2];
    float v1 = (y6[1] - L[2][1]*v2 - L[3][1]*v3 - L[4][1]*v4 - L[5][1]*v5) * isd[1];
    float v0 = (y6[0] - L[1][0]*v1 - L[2][0]*v2 - L[3][0]*v3 - L[4][0]*v4 - L[5][0]*v5) * isd[0];

    // ---- 3x3 symmetric eigenvalue ratio (closed form, f32) ----
    float a = v0, b = v1, cc = v2, d = v3, e = v4, f = v5;
    float ev0, ev1, ev2;
    float off = d * d + e * e + f * f;
    if (off == 0.0f) {
        ev0 = a; ev1 = b; ev2 = cc;
    } else {
        float q = (a + b + cc) * (1.0f / 3.0f);
        float p2 = (a-q)*(a-q) + (b-q)*(b-q) + (cc-q)*(cc-q) + 2.0f * off;
        float p = sqrtf(p2 * (1.0f / 6.0f));
        float ip = __builtin_amdgcn_rcpf(p);
        float b00 = (a - q) * ip, b11 = (b - q) * ip, b22 = (cc - q) * ip;
        float b01 = d * ip, b02 = e * ip, b12 = f * ip;
        float detB = b00 * (b11 * b22 - b12 * b12)
                   - b01 * (b01 * b22 - b12 * b02)
                   + b02 * (b01 * b12 - b11 * b02);
        float rq = 0.5f * detB;
        rq = fminf(1.0f, fmaxf(-1.0f, rq));
        float phi = acosf(rq) * (1.0f / 3.0f);
        ev0 = q + 2.0f * p * cosf(phi);
        ev2 = q + 2.0f * p * cosf(phi + (float)(2.0 * M_PI / 3.0));
        ev1 = 3.0f * q - ev0 - ev2;
    }
    float A0 = fabsf(ev0), A1 = fabsf(ev1), A2 = fabsf(ev2);
    float mx = fmaxf(A0, fmaxf(A1, A2));
    float mn = fminf(A0, fminf(A1, A2));
    float simi = sqrtf(fmaxf(mn, 1e-9f) / fmaxf(mx, 1e-9f));

    out[pi * 128 + pj] = simi;
}

extern "C" void kernel_launch(void* const* d_in, const int* in_sizes, int n_in,
                              void* d_out, int out_size, void* d_ws, size_t ws_size,
                              hipStream_t stream) {
    const float* depth = (const float*)d_in[0];
    float* out = (float*)d_out;
    curv_kernel<<<dim3(256), dim3(64), 0, stream>>>(depth, out);
}